// Round 2
// baseline (509.970 us; speedup 1.0000x reference)
//
#include <hip/hip_runtime.h>
#include <hip/hip_bf16.h>

// Shapes (fixed): B=8, Cin=512, N=2048, Ck=256, Co=512.
// hi/lo bf16 split (3-MFMA fp32 emulation) for projections + QK^T; plain bf16
// for P*V. Kernels: transpose/convert, W convert, 2 GEMMs, flash (m-split x2),
// combine.
// R2 changes vs R1 (flash was latency-bound: 11% occupancy, 1 wave/SIMD):
//  - V read from global (L2-resident) instead of LDS  -> LDS 132KB -> 70.6KB
//  - m-split x2: 512 blocks -> 2 blocks/CU, 2 waves/SIMD, independent barriers
//  - sP padded to 40-elem rows (kills 8-way conflict on pf reads)
//  - bf16 partials aliased over dead xt region (ws ~86MB, less than R1's 103MB)

typedef __bf16 bf16;
typedef __bf16 bf16x8 __attribute__((ext_vector_type(8)));
typedef __bf16 bf16x4 __attribute__((ext_vector_type(4)));
typedef float  f32x4  __attribute__((ext_vector_type(4)));

#define B_   8
#define N_   2048
#define CIN_ 512
#define CO_  512

__device__ __forceinline__ f32x4 mfma16(bf16x8 a, bf16x8 b, f32x4 c) {
  return __builtin_amdgcn_mfma_f32_16x16x32_bf16(a, b, c, 0, 0, 0);
}

__device__ __forceinline__ void gld_lds16(const bf16* g, bf16* l) {
  __builtin_amdgcn_global_load_lds(
      (const __attribute__((address_space(1))) void*)g,
      (__attribute__((address_space(3))) void*)l,
      16, 0, 0);
}

// ---------------- kernel 1: x (B,Cin,N) f32 -> xt (B,N,Cin) hi/lo bf16 ------
__global__ __launch_bounds__(256) void xt_kernel(const float* __restrict__ x,
                                                 bf16* __restrict__ xt_h,
                                                 bf16* __restrict__ xt_l) {
  __shared__ float tile[32][33];
  const int b = blockIdx.z;
  const int n0 = blockIdx.x * 32, c0 = blockIdx.y * 32;
  const int tx = threadIdx.x, ty = threadIdx.y;  // (32, 8)
  const float* xp = x + (size_t)b * CIN_ * N_;
#pragma unroll
  for (int j = 0; j < 4; j++)
    tile[ty + 8 * j][tx] = xp[(size_t)(c0 + ty + 8 * j) * N_ + n0 + tx];
  __syncthreads();
#pragma unroll
  for (int j = 0; j < 4; j++) {
    const int nl = ty + 8 * j, cl = tx;
    const float v = tile[cl][nl];
    const bf16 h = (bf16)v;
    const size_t o = (size_t)b * N_ * CIN_ + (size_t)(n0 + nl) * CIN_ + c0 + cl;
    xt_h[o] = h;
    xt_l[o] = (bf16)(v - (float)h);
  }
}

// ---------------- kernel 2: W rows [Wq(256); Wk(256); Wv(512)] -> hi/lo -----
__global__ __launch_bounds__(256) void w_kernel(const float* __restrict__ Wq,
                                                const float* __restrict__ Wk,
                                                const float* __restrict__ Wv,
                                                bf16* __restrict__ w_h,
                                                bf16* __restrict__ w_l) {
  const int idx = blockIdx.x * 256 + threadIdx.x;  // < 1024*512
  const int row = idx >> 9;
  float v;
  if (row < 256)       v = Wq[idx];
  else if (row < 512)  v = Wk[idx - 256 * 512];
  else                 v = Wv[idx - 512 * 512];
  const bf16 h = (bf16)v;
  w_h[idx] = h;
  w_l[idx] = (bf16)(v - (float)h);
}

// ---------------- kernel 3/4: hi/lo GEMM, D[row,col] = sum_k A[row,k]B[col,k]
__global__ __launch_bounds__(256) void gemm_hilo(
    const bf16* __restrict__ Ah, const bf16* __restrict__ Al, size_t sA,
    const bf16* __restrict__ Bh, const bf16* __restrict__ Bl, size_t sB,
    bf16* __restrict__ Dh, bf16* __restrict__ Dl, size_t sD,
    int lda, int ldb, int ldd, int store_lo) {
  __shared__ bf16 smA[2][2][128 * 32];  // [buf][hi/lo][row][k]
  __shared__ bf16 smB[2][2][128 * 32];  // [buf][hi/lo][col][k]
  const int tid = threadIdx.x;
  const int wave = tid >> 6, lane = tid & 63;
  const int l15 = lane & 15, l4 = lane >> 4;
  const int bz = blockIdx.z;
  const int row0 = blockIdx.x * 128, col0 = blockIdx.y * 128;
  const bf16* pAh = Ah + (size_t)bz * sA + (size_t)row0 * lda;
  const bf16* pAl = Al + (size_t)bz * sA + (size_t)row0 * lda;
  const bf16* pBh = Bh + (size_t)bz * sB + (size_t)col0 * ldb;
  const bf16* pBl = Bl + (size_t)bz * sB + (size_t)col0 * ldb;

  auto stage = [&](int buf, int kt) {
    const int k0 = kt * 32;
#pragma unroll
    for (int i = 0; i < 2; i++) {
      const int sb = i * 256 + wave * 64;
      const int s = sb + lane;
      const int r = s >> 2, kseg = (s & 3) * 8;
      gld_lds16(pAh + (size_t)r * lda + k0 + kseg, &smA[buf][0][sb * 8]);
    }
#pragma unroll
    for (int i = 0; i < 2; i++) {
      const int sb = i * 256 + wave * 64;
      const int s = sb + lane;
      const int r = s >> 2, kseg = (s & 3) * 8;
      gld_lds16(pAl + (size_t)r * lda + k0 + kseg, &smA[buf][1][sb * 8]);
    }
#pragma unroll
    for (int i = 0; i < 2; i++) {
      const int sb = i * 256 + wave * 64;
      const int s = sb + lane;
      const int c = s >> 2, kseg = (s & 3) * 8;
      gld_lds16(pBh + (size_t)c * ldb + k0 + kseg, &smB[buf][0][sb * 8]);
    }
#pragma unroll
    for (int i = 0; i < 2; i++) {
      const int sb = i * 256 + wave * 64;
      const int s = sb + lane;
      const int c = s >> 2, kseg = (s & 3) * 8;
      gld_lds16(pBl + (size_t)c * ldb + k0 + kseg, &smB[buf][1][sb * 8]);
    }
  };

  f32x4 acc[4][4];
  const f32x4 zero = {0.f, 0.f, 0.f, 0.f};
#pragma unroll
  for (int i = 0; i < 4; i++)
#pragma unroll
    for (int j = 0; j < 4; j++) acc[i][j] = zero;

  const int wrow = (wave >> 1) * 64, wcol = (wave & 1) * 64;
  stage(0, 0);
  __syncthreads();
  int buf = 0;
  for (int kt = 0; kt < 16; kt++) {
    if (kt < 15) stage(buf ^ 1, kt + 1);
    bf16x8 afh[4], afl[4], bfh[4], bfl[4];
    const int kk = l4 * 8;
#pragma unroll
    for (int f = 0; f < 4; f++) {
      const int ar = wrow + f * 16 + l15;
      afh[f] = *(const bf16x8*)&smA[buf][0][ar * 32 + kk];
      afl[f] = *(const bf16x8*)&smA[buf][1][ar * 32 + kk];
      const int bc = wcol + f * 16 + l15;
      bfh[f] = *(const bf16x8*)&smB[buf][0][bc * 32 + kk];
      bfl[f] = *(const bf16x8*)&smB[buf][1][bc * 32 + kk];
    }
#pragma unroll
    for (int fi = 0; fi < 4; fi++)
#pragma unroll
      for (int fj = 0; fj < 4; fj++) {
        f32x4 c = acc[fi][fj];
        c = mfma16(afh[fi], bfh[fj], c);
        c = mfma16(afh[fi], bfl[fj], c);
        c = mfma16(afl[fi], bfh[fj], c);
        acc[fi][fj] = c;
      }
    __syncthreads();
    buf ^= 1;
  }
  bf16* pDh = Dh + (size_t)bz * sD;
  bf16* pDl = Dl + (size_t)bz * sD;
#pragma unroll
  for (int fi = 0; fi < 4; fi++)
#pragma unroll
    for (int fj = 0; fj < 4; fj++)
#pragma unroll
      for (int r = 0; r < 4; r++) {
        const int row = row0 + wrow + fi * 16 + l4 * 4 + r;
        const int col = col0 + wcol + fj * 16 + l15;
        const float v = acc[fi][fj][r];
        const bf16 h = (bf16)v;
        pDh[(size_t)row * ldd + col] = h;
        if (store_lo) pDl[(size_t)row * ldd + col] = (bf16)(v - (float)h);
      }
}

// ---------------- kernel 5: flash attention (m-split x2) --------------------
// grid 512 = (nb=32) x (ms=2) x (b=8), XCD-bijective swizzled so each XCD
// serves one batch. 4 waves; wave owns 16 n; 32 iters of 32 m.
// K staged in LDS (XOR swizzle); V read straight from global (L2-resident).
// Writes unnormalized bf16 partial + per-n (m,l) stats; combine merges.
__global__ __launch_bounds__(256, 2) void flash_kernel(
    const bf16* __restrict__ qkt_h, const bf16* __restrict__ qkt_l,
    const bf16* __restrict__ vmat, bf16* __restrict__ pacc,
    float* __restrict__ mstat, float* __restrict__ lstat) {
  __shared__ bf16 sK[2][2][32 * 256];  // [buf][hi/lo][m][k] (swizzled) 64KB
  __shared__ bf16 sP[4][16][40];       // [wave][n][m-padded]          5KB
  const int tid = threadIdx.x, wave = tid >> 6, lane = tid & 63;
  const int l15 = lane & 15, l4 = lane >> 4;
  // XCD-bijective swizzle: 512 blocks, 8 XCDs, 64 blocks/XCD = one batch each
  const int bid = blockIdx.x;
  const int wgid = (bid & 7) * 64 + (bid >> 3);
  const int b = wgid >> 6, ms = (wgid >> 5) & 1, nb = wgid & 31;
  const int n0 = nb * 64 + wave * 16;
  const int mbase = ms * 1024;
  const bf16* qh_base = qkt_h + (size_t)b * N_ * 512;
  const bf16* ql_base = qkt_l + (size_t)b * N_ * 512;
  const bf16* v_base = vmat + (size_t)b * CO_ * N_;

  // Q fragments in registers: 16 n-rows x 256 k, hi/lo
  bf16x8 qh[8], ql[8];
  {
    const int nr = n0 + l15;
#pragma unroll
    for (int ks = 0; ks < 8; ks++) {
      const size_t off = (size_t)nr * 512 + ks * 32 + l4 * 8;
      qh[ks] = *(const bf16x8*)(qh_base + off);
      ql[ks] = *(const bf16x8*)(ql_base + off);
    }
  }
  f32x4 acc[32];
  const f32x4 zero = {0.f, 0.f, 0.f, 0.f};
#pragma unroll
  for (int i = 0; i < 32; i++) acc[i] = zero;
  float run_m = -3e38f, run_l = 0.f;

  auto stage = [&](int bufi, int mt) {
    const int m0 = mbase + mt * 32;
#pragma unroll
    for (int h = 0; h < 2; h++) {
      const bf16* src = (h ? ql_base : qh_base) + 256;  // K cols 256..511
#pragma unroll
      for (int i = 0; i < 4; i++) {
        const int sb = i * 256 + wave * 64, s = sb + lane;
        const int m = s >> 5;
        const int kseg = ((s & 31) * 8) ^ ((m & 7) << 3);
        gld_lds16(src + (size_t)(m0 + m) * 512 + kseg, &sK[bufi][h][sb * 8]);
      }
    }
  };

  stage(0, 0);
  __syncthreads();
  int buf = 0;
  for (int mt = 0; mt < 32; mt++) {
    const int m0 = mbase + mt * 32;
    if (mt < 31) stage(buf ^ 1, mt + 1);
    // S^T (two 16m x 16n fragments), hi/lo 3-term
    f32x4 sfr[2];
#pragma unroll
    for (int msf = 0; msf < 2; msf++) {
      f32x4 aA = zero, aB = zero;
      const int krow = msf * 16 + l15;
      const int swz = (krow & 7) << 3;
      const bf16* kh_p = &sK[buf][0][krow * 256];
      const bf16* kl_p = &sK[buf][1][krow * 256];
#pragma unroll
      for (int ks = 0; ks < 8; ks++) {
        const int ke = (ks * 32 + l4 * 8) ^ swz;
        const bf16x8 kh = *(const bf16x8*)(kh_p + ke);
        const bf16x8 kl = *(const bf16x8*)(kl_p + ke);
        aA = mfma16(kh, qh[ks], aA);
        aB = mfma16(kh, ql[ks], aB);
        aB = mfma16(kl, qh[ks], aB);
      }
      sfr[msf] = aA + aB;
    }
    // online softmax over m (lane owns column n = n0 + l15)
    float tmax = -3e38f;
#pragma unroll
    for (int msf = 0; msf < 2; msf++)
#pragma unroll
      for (int r = 0; r < 4; r++) tmax = fmaxf(tmax, sfr[msf][r]);
    tmax = fmaxf(tmax, __shfl_xor(tmax, 16));
    tmax = fmaxf(tmax, __shfl_xor(tmax, 32));
    const float nm = fmaxf(run_m, tmax);
    const float corr = __expf(run_m - nm);
    float tsum = 0.f;
#pragma unroll
    for (int msf = 0; msf < 2; msf++) {
      bf16x4 pk;
#pragma unroll
      for (int r = 0; r < 4; r++) {
        const float p = __expf(sfr[msf][r] - nm);
        tsum += p;
        pk[r] = (bf16)p;
      }
      *(bf16x4*)&sP[wave][l15][msf * 16 + l4 * 4] = pk;
    }
    tsum += __shfl_xor(tsum, 16);
    tsum += __shfl_xor(tsum, 32);
    run_l = run_l * corr + tsum;
    run_m = nm;
#pragma unroll
    for (int i = 0; i < 32; i++) acc[i] = acc[i] * corr;
    // PV: acc[of] += V[o][m] * P^T[m][n]; V from global (L2), chunks of 8
    const bf16x8 pf = *(const bf16x8*)&sP[wave][l15][l4 * 8];
    const bf16* vrow = v_base + (size_t)l15 * N_ + m0 + l4 * 8;
#pragma unroll
    for (int c = 0; c < 4; c++) {
      bf16x8 vf[8];
#pragma unroll
      for (int i = 0; i < 8; i++)
        vf[i] = *(const bf16x8*)(vrow + (size_t)(c * 8 + i) * 16 * N_);
#pragma unroll
      for (int i = 0; i < 8; i++)
        acc[c * 8 + i] = mfma16(vf[i], pf, acc[c * 8 + i]);
    }
    __syncthreads();
    buf ^= 1;
  }
  // write unnormalized partial (bf16) + stats
  bf16* pbase = pacc + (size_t)ms * (B_ * (size_t)CO_ * N_) +
                ((size_t)b * CO_) * N_;
#pragma unroll
  for (int of = 0; of < 32; of++)
#pragma unroll
    for (int r = 0; r < 4; r++) {
      const int o = of * 16 + l4 * 4 + r;
      pbase[(size_t)o * N_ + n0 + l15] = (bf16)acc[of][r];
    }
  if (l4 == 0) {
    const int si = ms * (B_ * N_) + b * N_ + n0 + l15;
    mstat[si] = run_m;
    lstat[si] = run_l;
  }
}

// ---------------- kernel 6: combine the two m-split partials ----------------
__global__ __launch_bounds__(256) void combine_kernel(
    const bf16* __restrict__ pacc, const float* __restrict__ mstat,
    const float* __restrict__ lstat, float* __restrict__ out) {
  const size_t XT = (size_t)B_ * CO_ * N_;
  const size_t t = (size_t)blockIdx.x * 256 + threadIdx.x;  // 1,048,576
  const int n0 = (int)(t & 255) * 8;
  const int o = (int)((t >> 8) & 511);
  const int b = (int)(t >> 17);
  const size_t po = ((size_t)b * CO_ + o) * N_ + n0;
  const bf16x8 p1 = *(const bf16x8*)(pacc + po);
  const bf16x8 p2 = *(const bf16x8*)(pacc + XT + po);
  const int sb = b * N_ + n0;
  f32x4 r0, r1;
#pragma unroll
  for (int j = 0; j < 8; j++) {
    const float m1 = mstat[sb + j], m2 = mstat[B_ * N_ + sb + j];
    const float l1 = lstat[sb + j], l2 = lstat[B_ * N_ + sb + j];
    const float M = fmaxf(m1, m2);
    const float a1 = __expf(m1 - M), a2 = __expf(m2 - M);
    const float L = a1 * l1 + a2 * l2;
    const float v = ((float)p1[j] * a1 + (float)p2[j] * a2) / L;
    if (j < 4) r0[j] = v; else r1[j - 4] = v;
  }
  *(f32x4*)(out + po) = r0;
  *(f32x4*)(out + po + 4) = r1;
}

// ---------------- launcher ---------------------------------------------------
extern "C" void kernel_launch(void* const* d_in, const int* in_sizes, int n_in,
                              void* d_out, int out_size, void* d_ws,
                              size_t ws_size, hipStream_t stream) {
  const float* x = (const float*)d_in[0];
  const float* Wq = (const float*)d_in[1];
  const float* Wk = (const float*)d_in[2];
  const float* Wv = (const float*)d_in[3];
  float* out = (float*)d_out;
  bf16* ws = (bf16*)d_ws;

  const size_t XT = (size_t)B_ * N_ * CIN_;  // 8,388,608 elems (also B*Co*N)
  const size_t XTB = (size_t)N_ * CIN_;      // per-batch stride 1,048,576
  // layout (bf16 elems): [qk_h XT][qk_l XT][v_h XT][xt_h XT][xt_l XT][w 1M][stats]
  bf16* qk_h = ws;
  bf16* qk_l = ws + XT;
  bf16* v_h = ws + 2 * XT;
  bf16* xt_h = ws + 3 * XT;             // aliased by partial after gemms
  bf16* xt_l = ws + 4 * XT;
  bf16* pacc = xt_h;                    // 2*XT bf16 partials
  bf16* w_h = ws + 5 * XT;
  bf16* w_l = w_h + 1024 * 512;
  float* mstat = (float*)(w_l + 1024 * 512);   // 2*8*2048 f32
  float* lstat = mstat + 2 * B_ * N_;
  // total ws use ~86.5 MB (< R1's 102.8 MB which worked)

  xt_kernel<<<dim3(64, 16, 8), dim3(32, 8, 1), 0, stream>>>(x, xt_h, xt_l);
  w_kernel<<<dim3(2048), dim3(256), 0, stream>>>(Wq, Wk, Wv, w_h, w_l);
  // QKt (B, N, 512): rows n, cols (Q|K)
  gemm_hilo<<<dim3(16, 4, 8), dim3(256), 0, stream>>>(
      xt_h, xt_l, XTB, w_h, w_l, (size_t)0, qk_h, qk_l, XTB, 512, 512, 512, 1);
  // V (B, 512, N): rows o, cols n (no lo stored)
  gemm_hilo<<<dim3(4, 16, 8), dim3(256), 0, stream>>>(
      w_h + 512 * 512, w_l + 512 * 512, (size_t)0, xt_h, xt_l, XTB, v_h, v_h,
      (size_t)(CO_ * N_), 512, 512, 2048, 0);
  flash_kernel<<<dim3(512), dim3(256), 0, stream>>>(qk_h, qk_l, v_h, pacc,
                                                    mstat, lstat);
  combine_kernel<<<dim3(4096), dim3(256), 0, stream>>>(pacc, mstat, lstat, out);
}

// Round 6
// 489.059 us; speedup vs baseline: 1.0428x; 1.0428x over previous
//
#include <hip/hip_runtime.h>
#include <hip/hip_bf16.h>

// Shapes (fixed): B=8, Cin=512, N=2048, Ck=256, Co=512.
// hi/lo bf16 split (3-MFMA fp32 emulation) for projections + QK^T; plain bf16
// for P*V. Kernels: transpose/convert, W convert, 2 GEMMs, flash.
// R3 changes vs R2 (V L2-latency was serialized; MfmaUtil/VALU both ~10%):
//  - wave owns 32 n (2 n-frags) -> every K fragment feeds 6 MFMAs (halves
//    K-LDS traffic per unit n)
//  - o-split x4 across blocks (block = 128 o x 128 n, full o per wave,
//    acc = 64 f32) -> no m-split, no partials, no combine; direct f32 out
//  - V frags from L2 issued right after QK^T, consumed after softmax+sP
//    round-trip (~350cy distance), staggered 4+4 to cap VGPRs
//  - K in swizzled dbuf LDS (64KB) + sP 10KB = 75KB -> 2 blocks/CU
// (R6 = identical resubmit; R3/R4/R5 benches were broker timeouts, no data.)

typedef __bf16 bf16;
typedef __bf16 bf16x8 __attribute__((ext_vector_type(8)));
typedef __bf16 bf16x4 __attribute__((ext_vector_type(4)));
typedef float  f32x4  __attribute__((ext_vector_type(4)));

#define B_   8
#define N_   2048
#define CIN_ 512
#define CO_  512

__device__ __forceinline__ f32x4 mfma16(bf16x8 a, bf16x8 b, f32x4 c) {
  return __builtin_amdgcn_mfma_f32_16x16x32_bf16(a, b, c, 0, 0, 0);
}

__device__ __forceinline__ void gld_lds16(const bf16* g, bf16* l) {
  __builtin_amdgcn_global_load_lds(
      (const __attribute__((address_space(1))) void*)g,
      (__attribute__((address_space(3))) void*)l,
      16, 0, 0);
}

// ---------------- kernel 1: x (B,Cin,N) f32 -> xt (B,N,Cin) hi/lo bf16 ------
__global__ __launch_bounds__(256) void xt_kernel(const float* __restrict__ x,
                                                 bf16* __restrict__ xt_h,
                                                 bf16* __restrict__ xt_l) {
  __shared__ float tile[32][33];
  const int b = blockIdx.z;
  const int n0 = blockIdx.x * 32, c0 = blockIdx.y * 32;
  const int tx = threadIdx.x, ty = threadIdx.y;  // (32, 8)
  const float* xp = x + (size_t)b * CIN_ * N_;
#pragma unroll
  for (int j = 0; j < 4; j++)
    tile[ty + 8 * j][tx] = xp[(size_t)(c0 + ty + 8 * j) * N_ + n0 + tx];
  __syncthreads();
#pragma unroll
  for (int j = 0; j < 4; j++) {
    const int nl = ty + 8 * j, cl = tx;
    const float v = tile[cl][nl];
    const bf16 h = (bf16)v;
    const size_t o = (size_t)b * N_ * CIN_ + (size_t)(n0 + nl) * CIN_ + c0 + cl;
    xt_h[o] = h;
    xt_l[o] = (bf16)(v - (float)h);
  }
}

// ---------------- kernel 2: W rows [Wq(256); Wk(256); Wv(512)] -> hi/lo -----
__global__ __launch_bounds__(256) void w_kernel(const float* __restrict__ Wq,
                                                const float* __restrict__ Wk,
                                                const float* __restrict__ Wv,
                                                bf16* __restrict__ w_h,
                                                bf16* __restrict__ w_l) {
  const int idx = blockIdx.x * 256 + threadIdx.x;  // < 1024*512
  const int row = idx >> 9;
  float v;
  if (row < 256)       v = Wq[idx];
  else if (row < 512)  v = Wk[idx - 256 * 512];
  else                 v = Wv[idx - 512 * 512];
  const bf16 h = (bf16)v;
  w_h[idx] = h;
  w_l[idx] = (bf16)(v - (float)h);
}

// ---------------- kernel 3/4: hi/lo GEMM, D[row,col] = sum_k A[row,k]B[col,k]
__global__ __launch_bounds__(256) void gemm_hilo(
    const bf16* __restrict__ Ah, const bf16* __restrict__ Al, size_t sA,
    const bf16* __restrict__ Bh, const bf16* __restrict__ Bl, size_t sB,
    bf16* __restrict__ Dh, bf16* __restrict__ Dl, size_t sD,
    int lda, int ldb, int ldd, int store_lo) {
  __shared__ bf16 smA[2][2][128 * 32];  // [buf][hi/lo][row][k]
  __shared__ bf16 smB[2][2][128 * 32];  // [buf][hi/lo][col][k]
  const int tid = threadIdx.x;
  const int wave = tid >> 6, lane = tid & 63;
  const int l15 = lane & 15, l4 = lane >> 4;
  const int bz = blockIdx.z;
  const int row0 = blockIdx.x * 128, col0 = blockIdx.y * 128;
  const bf16* pAh = Ah + (size_t)bz * sA + (size_t)row0 * lda;
  const bf16* pAl = Al + (size_t)bz * sA + (size_t)row0 * lda;
  const bf16* pBh = Bh + (size_t)bz * sB + (size_t)col0 * ldb;
  const bf16* pBl = Bl + (size_t)bz * sB + (size_t)col0 * ldb;

  auto stage = [&](int buf, int kt) {
    const int k0 = kt * 32;
#pragma unroll
    for (int i = 0; i < 2; i++) {
      const int sb = i * 256 + wave * 64;
      const int s = sb + lane;
      const int r = s >> 2, kseg = (s & 3) * 8;
      gld_lds16(pAh + (size_t)r * lda + k0 + kseg, &smA[buf][0][sb * 8]);
    }
#pragma unroll
    for (int i = 0; i < 2; i++) {
      const int sb = i * 256 + wave * 64;
      const int s = sb + lane;
      const int r = s >> 2, kseg = (s & 3) * 8;
      gld_lds16(pAl + (size_t)r * lda + k0 + kseg, &smA[buf][1][sb * 8]);
    }
#pragma unroll
    for (int i = 0; i < 2; i++) {
      const int sb = i * 256 + wave * 64;
      const int s = sb + lane;
      const int c = s >> 2, kseg = (s & 3) * 8;
      gld_lds16(pBh + (size_t)c * ldb + k0 + kseg, &smB[buf][0][sb * 8]);
    }
#pragma unroll
    for (int i = 0; i < 2; i++) {
      const int sb = i * 256 + wave * 64;
      const int s = sb + lane;
      const int c = s >> 2, kseg = (s & 3) * 8;
      gld_lds16(pBl + (size_t)c * ldb + k0 + kseg, &smB[buf][1][sb * 8]);
    }
  };

  f32x4 acc[4][4];
  const f32x4 zero = {0.f, 0.f, 0.f, 0.f};
#pragma unroll
  for (int i = 0; i < 4; i++)
#pragma unroll
    for (int j = 0; j < 4; j++) acc[i][j] = zero;

  const int wrow = (wave >> 1) * 64, wcol = (wave & 1) * 64;
  stage(0, 0);
  __syncthreads();
  int buf = 0;
  for (int kt = 0; kt < 16; kt++) {
    if (kt < 15) stage(buf ^ 1, kt + 1);
    bf16x8 afh[4], afl[4], bfh[4], bfl[4];
    const int kk = l4 * 8;
#pragma unroll
    for (int f = 0; f < 4; f++) {
      const int ar = wrow + f * 16 + l15;
      afh[f] = *(const bf16x8*)&smA[buf][0][ar * 32 + kk];
      afl[f] = *(const bf16x8*)&smA[buf][1][ar * 32 + kk];
      const int bc = wcol + f * 16 + l15;
      bfh[f] = *(const bf16x8*)&smB[buf][0][bc * 32 + kk];
      bfl[f] = *(const bf16x8*)&smB[buf][1][bc * 32 + kk];
    }
#pragma unroll
    for (int fi = 0; fi < 4; fi++)
#pragma unroll
      for (int fj = 0; fj < 4; fj++) {
        f32x4 c = acc[fi][fj];
        c = mfma16(afh[fi], bfh[fj], c);
        c = mfma16(afh[fi], bfl[fj], c);
        c = mfma16(afl[fi], bfh[fj], c);
        acc[fi][fj] = c;
      }
    __syncthreads();
    buf ^= 1;
  }
  bf16* pDh = Dh + (size_t)bz * sD;
  bf16* pDl = Dl + (size_t)bz * sD;
#pragma unroll
  for (int fi = 0; fi < 4; fi++)
#pragma unroll
    for (int fj = 0; fj < 4; fj++)
#pragma unroll
      for (int r = 0; r < 4; r++) {
        const int row = row0 + wrow + fi * 16 + l4 * 4 + r;
        const int col = col0 + wcol + fj * 16 + l15;
        const float v = acc[fi][fj][r];
        const bf16 h = (bf16)v;
        pDh[(size_t)row * ldd + col] = h;
        if (store_lo) pDl[(size_t)row * ldd + col] = (bf16)(v - (float)h);
      }
}

// ---------------- kernel 5: flash attention ---------------------------------
// grid 512 = (nb=16) x (os=4) x (b=8), batch-per-XCD swizzle. 4 waves.
// Wave: 32 n (2 frags), full block o-range (128 = 8 frags), sweeps all 2048 m.
// K hi/lo in swizzled dbuf LDS; V frags direct from L2 with ~350cy cover;
// P via per-wave sP (padded). Direct f32 output, no combine.
__global__ __launch_bounds__(256, 2) void flash_kernel(
    const bf16* __restrict__ qkt_h, const bf16* __restrict__ qkt_l,
    const bf16* __restrict__ vmat, float* __restrict__ out) {
  __shared__ bf16 sK[2][2][32 * 256];  // [buf][hi/lo][m][k] swizzled, 64KB
  __shared__ bf16 sP[4][32][40];       // [wave][n][m-padded], 10KB
  const int tid = threadIdx.x, wave = tid >> 6, lane = tid & 63;
  const int l15 = lane & 15, l4 = lane >> 4;
  // 512 blocks, 8 XCDs -> 64 blocks/XCD = one batch per XCD
  const int bid = blockIdx.x;
  const int wgid = (bid & 7) * 64 + (bid >> 3);
  const int b = wgid >> 6;
  const int os = (wgid >> 4) & 3;
  const int nb = wgid & 15;
  const int n0 = nb * 128 + wave * 32;
  const int oB = os * 128;
  const bf16* qh_base = qkt_h + (size_t)b * N_ * 512;
  const bf16* ql_base = qkt_l + (size_t)b * N_ * 512;
  const bf16* v_base = vmat + (size_t)b * CO_ * N_;

  // Q fragments in registers: 32 n-rows x 256 k, hi/lo (128 VGPRs)
  bf16x8 qh0[8], ql0[8], qh1[8], ql1[8];
  {
    const size_t r0 = (size_t)(n0 + l15) * 512 + l4 * 8;
    const size_t r1 = (size_t)(n0 + 16 + l15) * 512 + l4 * 8;
#pragma unroll
    for (int ks = 0; ks < 8; ks++) {
      qh0[ks] = *(const bf16x8*)(qh_base + r0 + ks * 32);
      ql0[ks] = *(const bf16x8*)(ql_base + r0 + ks * 32);
      qh1[ks] = *(const bf16x8*)(qh_base + r1 + ks * 32);
      ql1[ks] = *(const bf16x8*)(ql_base + r1 + ks * 32);
    }
  }

  f32x4 acc[8][2];
  const f32x4 zero = {0.f, 0.f, 0.f, 0.f};
#pragma unroll
  for (int of = 0; of < 8; of++) {
    acc[of][0] = zero;
    acc[of][1] = zero;
  }
  float run_m0 = -3e38f, run_l0 = 0.f;
  float run_m1 = -3e38f, run_l1 = 0.f;

  // K staging: per-lane source offsets are iteration-invariant
  const bf16* kh_g = qh_base + 256;  // K = cols 256..511
  const bf16* kl_g = ql_base + 256;
  int srcoff[4];
#pragma unroll
  for (int g = 0; g < 4; g++) {
    const int chunk = wave * 256 + g * 64 + lane;
    const int m = chunk >> 5, c31 = chunk & 31;
    srcoff[g] = m * 512 + (c31 ^ (m & 7)) * 8;  // pre-swizzled global source
  }

  auto stage = [&](int bufi, int mt) {
    const int mo = mt * 16384;  // (mt*32)*512
#pragma unroll
    for (int g = 0; g < 4; g++) {
      const int db = (wave * 256 + g * 64) * 8;
      gld_lds16(kh_g + mo + srcoff[g], &sK[bufi][0][db]);
      gld_lds16(kl_g + mo + srcoff[g], &sK[bufi][1][db]);
    }
  };

  stage(0, 0);
  __syncthreads();
  int buf = 0;
  const int kb0 = l15 * 256;         // mf0 row (m = l15)
  const int kb1 = (16 + l15) * 256;  // mf1 row (m = 16+l15)
  const int sw = (l15 & 7) << 3;     // same for both rows ((16+l15)&7 == l15&7)

  for (int mt = 0; mt < 64; mt++) {
    const int m0 = mt * 32;
    if (mt < 63) stage(buf ^ 1, mt + 1);
    // ---- QK^T: S[mf][nf], 3-term hi/lo, 96 MFMA ----
    f32x4 s00 = zero, s01 = zero, s10 = zero, s11 = zero;
#pragma unroll
    for (int ks = 0; ks < 8; ks++) {
      const int ke = (ks * 32 + l4 * 8) ^ sw;
      const bf16x8 kh0v = *(const bf16x8*)&sK[buf][0][kb0 + ke];
      const bf16x8 kl0v = *(const bf16x8*)&sK[buf][1][kb0 + ke];
      const bf16x8 kh1v = *(const bf16x8*)&sK[buf][0][kb1 + ke];
      const bf16x8 kl1v = *(const bf16x8*)&sK[buf][1][kb1 + ke];
      s00 = mfma16(kh0v, qh0[ks], s00);
      s01 = mfma16(kh0v, qh1[ks], s01);
      s10 = mfma16(kh1v, qh0[ks], s10);
      s11 = mfma16(kh1v, qh1[ks], s11);
      s00 = mfma16(kh0v, ql0[ks], s00);
      s01 = mfma16(kh0v, ql1[ks], s01);
      s10 = mfma16(kh1v, ql0[ks], s10);
      s11 = mfma16(kh1v, ql1[ks], s11);
      s00 = mfma16(kl0v, qh0[ks], s00);
      s01 = mfma16(kl0v, qh1[ks], s01);
      s10 = mfma16(kl1v, qh0[ks], s10);
      s11 = mfma16(kl1v, qh1[ks], s11);
    }
    // ---- issue first half of V frags (consumed after softmax) ----
    const bf16* vrow = v_base + (size_t)(oB + l15) * N_ + m0 + l4 * 8;
    bf16x8 vfA[4];
#pragma unroll
    for (int of = 0; of < 4; of++)
      vfA[of] = *(const bf16x8*)(vrow + (size_t)of * 16 * N_);
    // ---- online softmax per n-frag (lane column n = n0 + nf*16 + l15) ----
    float tm0 = fmaxf(fmaxf(fmaxf(s00[0], s00[1]), fmaxf(s00[2], s00[3])),
                      fmaxf(fmaxf(s10[0], s10[1]), fmaxf(s10[2], s10[3])));
    float tm1 = fmaxf(fmaxf(fmaxf(s01[0], s01[1]), fmaxf(s01[2], s01[3])),
                      fmaxf(fmaxf(s11[0], s11[1]), fmaxf(s11[2], s11[3])));
    tm0 = fmaxf(tm0, __shfl_xor(tm0, 16));
    tm0 = fmaxf(tm0, __shfl_xor(tm0, 32));
    tm1 = fmaxf(tm1, __shfl_xor(tm1, 16));
    tm1 = fmaxf(tm1, __shfl_xor(tm1, 32));
    const float nm0 = fmaxf(run_m0, tm0), nm1 = fmaxf(run_m1, tm1);
    const float c0 = __expf(run_m0 - nm0), c1 = __expf(run_m1 - nm1);
    float ts0 = 0.f, ts1 = 0.f;
    {
      bf16x4 pk0, pk1, pk2, pk3;
#pragma unroll
      for (int r = 0; r < 4; r++) {
        const float p00 = __expf(s00[r] - nm0);
        const float p10 = __expf(s10[r] - nm0);
        const float p01 = __expf(s01[r] - nm1);
        const float p11 = __expf(s11[r] - nm1);
        ts0 += p00 + p10;
        ts1 += p01 + p11;
        pk0[r] = (bf16)p00;
        pk1[r] = (bf16)p10;
        pk2[r] = (bf16)p01;
        pk3[r] = (bf16)p11;
      }
      *(bf16x4*)&sP[wave][l15][l4 * 4] = pk0;
      *(bf16x4*)&sP[wave][l15][16 + l4 * 4] = pk1;
      *(bf16x4*)&sP[wave][16 + l15][l4 * 4] = pk2;
      *(bf16x4*)&sP[wave][16 + l15][16 + l4 * 4] = pk3;
    }
    ts0 += __shfl_xor(ts0, 16);
    ts0 += __shfl_xor(ts0, 32);
    ts1 += __shfl_xor(ts1, 16);
    ts1 += __shfl_xor(ts1, 32);
    run_l0 = run_l0 * c0 + ts0;
    run_l1 = run_l1 * c1 + ts1;
    run_m0 = nm0;
    run_m1 = nm1;
#pragma unroll
    for (int of = 0; of < 8; of++) {
      acc[of][0] *= c0;
      acc[of][1] *= c1;
    }
    // ---- PV: acc[of][nf] += V[16o x 32m] * P[32m x 16n] ----
    bf16x8 vfB[4];
#pragma unroll
    for (int of = 0; of < 4; of++)
      vfB[of] = *(const bf16x8*)(vrow + (size_t)(of + 4) * 16 * N_);
    const bf16x8 pb0 = *(const bf16x8*)&sP[wave][l15][l4 * 8];
    const bf16x8 pb1 = *(const bf16x8*)&sP[wave][16 + l15][l4 * 8];
#pragma unroll
    for (int of = 0; of < 4; of++) {
      acc[of][0] = mfma16(vfA[of], pb0, acc[of][0]);
      acc[of][1] = mfma16(vfA[of], pb1, acc[of][1]);
    }
#pragma unroll
    for (int of = 0; of < 4; of++) {
      acc[of + 4][0] = mfma16(vfB[of], pb0, acc[of + 4][0]);
      acc[of + 4][1] = mfma16(vfB[of], pb1, acc[of + 4][1]);
    }
    __syncthreads();
    buf ^= 1;
  }
  // ---- epilogue: normalize and write f32 out (B, Co, N) ----
  const float inv0 = 1.f / run_l0, inv1 = 1.f / run_l1;
  float* obase = out + (size_t)b * CO_ * N_;
#pragma unroll
  for (int of = 0; of < 8; of++)
#pragma unroll
    for (int r = 0; r < 4; r++) {
      const int o = oB + of * 16 + l4 * 4 + r;
      obase[(size_t)o * N_ + n0 + l15] = acc[of][0][r] * inv0;
      obase[(size_t)o * N_ + n0 + 16 + l15] = acc[of][1][r] * inv1;
    }
}

// ---------------- launcher ---------------------------------------------------
extern "C" void kernel_launch(void* const* d_in, const int* in_sizes, int n_in,
                              void* d_out, int out_size, void* d_ws,
                              size_t ws_size, hipStream_t stream) {
  const float* x = (const float*)d_in[0];
  const float* Wq = (const float*)d_in[1];
  const float* Wk = (const float*)d_in[2];
  const float* Wv = (const float*)d_in[3];
  float* out = (float*)d_out;
  bf16* ws = (bf16*)d_ws;

  const size_t XT = (size_t)B_ * N_ * CIN_;  // 8,388,608 elems
  const size_t XTB = (size_t)N_ * CIN_;      // per-batch stride 1,048,576
  bf16* qk_h = ws;
  bf16* qk_l = ws + XT;
  bf16* v_h = ws + 2 * XT;
  bf16* xt_h = ws + 3 * XT;
  bf16* xt_l = ws + 4 * XT;
  bf16* w_h = ws + 5 * XT;
  bf16* w_l = w_h + 1024 * 512;
  // total ws use: 5*16.78MB + 2*1.05MB = ~86 MB

  xt_kernel<<<dim3(64, 16, 8), dim3(32, 8, 1), 0, stream>>>(x, xt_h, xt_l);
  w_kernel<<<dim3(2048), dim3(256), 0, stream>>>(Wq, Wk, Wv, w_h, w_l);
  // QKt (B, N, 512): rows n, cols (Q|K)
  gemm_hilo<<<dim3(16, 4, 8), dim3(256), 0, stream>>>(
      xt_h, xt_l, XTB, w_h, w_l, (size_t)0, qk_h, qk_l, XTB, 512, 512, 512, 1);
  // V (B, 512, N): rows o, cols n (no lo stored)
  gemm_hilo<<<dim3(4, 16, 8), dim3(256), 0, stream>>>(
      w_h + 512 * 512, w_l + 512 * 512, (size_t)0, xt_h, xt_l, XTB, v_h, v_h,
      (size_t)(CO_ * N_), 512, 512, 2048, 0);
  flash_kernel<<<dim3(512), dim3(256), 0, stream>>>(qk_h, qk_l, v_h, out);
}

// Round 8
// 280.865 us; speedup vs baseline: 1.8157x; 1.7413x over previous
//
#include <hip/hip_runtime.h>
#include <hip/hip_bf16.h>

// Shapes (fixed): B=8, Cin=512, N=2048, Ck=256, Co=512.
// hi/lo bf16 split for projections + QK^T; plain bf16 for P*V.
// R8 = R7 + softmax-consistency fix (R7 failed, absmax 11.66):
//   R7 bug: wave's PV acc spans all 128 n-cols of the block, but rescale used
//   the wave's OWN 16-col softmax state. Fix: owner wave publishes per-column
//   corr into sCorr[128] each iter; all waves scale acc[of][nf] by
//   sCorr[nf*16+l15] after the barrier, before accumulating PV. Owner keeps
//   run_m/run_l; combine (verified in R2) unchanged.

typedef __bf16 bf16;
typedef __bf16 bf16x8 __attribute__((ext_vector_type(8)));
typedef __bf16 bf16x4 __attribute__((ext_vector_type(4)));
typedef float  f32x4  __attribute__((ext_vector_type(4)));

#define B_   8
#define N_   2048
#define CIN_ 512
#define CO_  512

__device__ __forceinline__ f32x4 mfma16(bf16x8 a, bf16x8 b, f32x4 c) {
  return __builtin_amdgcn_mfma_f32_16x16x32_bf16(a, b, c, 0, 0, 0);
}

__device__ __forceinline__ void gld_lds16(const bf16* g, bf16* l) {
  __builtin_amdgcn_global_load_lds(
      (const __attribute__((address_space(1))) void*)g,
      (__attribute__((address_space(3))) void*)l,
      16, 0, 0);
}

// ---------------- kernel 1: x (B,Cin,N) f32 -> xt (B,N,Cin) hi/lo bf16 ------
__global__ __launch_bounds__(256) void xt_kernel(const float* __restrict__ x,
                                                 bf16* __restrict__ xt_h,
                                                 bf16* __restrict__ xt_l) {
  __shared__ float tile[32][33];
  const int b = blockIdx.z;
  const int n0 = blockIdx.x * 32, c0 = blockIdx.y * 32;
  const int tx = threadIdx.x, ty = threadIdx.y;  // (32, 8)
  const float* xp = x + (size_t)b * CIN_ * N_;
#pragma unroll
  for (int j = 0; j < 4; j++)
    tile[ty + 8 * j][tx] = xp[(size_t)(c0 + ty + 8 * j) * N_ + n0 + tx];
  __syncthreads();
#pragma unroll
  for (int j = 0; j < 4; j++) {
    const int nl = ty + 8 * j, cl = tx;
    const float v = tile[cl][nl];
    const bf16 h = (bf16)v;
    const size_t o = (size_t)b * N_ * CIN_ + (size_t)(n0 + nl) * CIN_ + c0 + cl;
    xt_h[o] = h;
    xt_l[o] = (bf16)(v - (float)h);
  }
}

// ---------------- kernel 2: W rows [Wq(256); Wk(256); Wv(512)] -> hi/lo -----
__global__ __launch_bounds__(256) void w_kernel(const float* __restrict__ Wq,
                                                const float* __restrict__ Wk,
                                                const float* __restrict__ Wv,
                                                bf16* __restrict__ w_h,
                                                bf16* __restrict__ w_l) {
  const int idx = blockIdx.x * 256 + threadIdx.x;  // < 1024*512
  const int row = idx >> 9;
  float v;
  if (row < 256)       v = Wq[idx];
  else if (row < 512)  v = Wk[idx - 256 * 512];
  else                 v = Wv[idx - 512 * 512];
  const bf16 h = (bf16)v;
  w_h[idx] = h;
  w_l[idx] = (bf16)(v - (float)h);
}

// ---------------- kernel 3/4: hi/lo GEMM, D[row,col] = sum_k A[row,k]B[col,k]
__global__ __launch_bounds__(256) void gemm_hilo(
    const bf16* __restrict__ Ah, const bf16* __restrict__ Al, size_t sA,
    const bf16* __restrict__ Bh, const bf16* __restrict__ Bl, size_t sB,
    bf16* __restrict__ Dh, bf16* __restrict__ Dl, size_t sD,
    int lda, int ldb, int ldd, int store_lo) {
  __shared__ bf16 smA[2][2][128 * 32];  // [buf][hi/lo][row][k]
  __shared__ bf16 smB[2][2][128 * 32];  // [buf][hi/lo][col][k]
  const int tid = threadIdx.x;
  const int wave = tid >> 6, lane = tid & 63;
  const int l15 = lane & 15, l4 = lane >> 4;
  const int bz = blockIdx.z;
  const int row0 = blockIdx.x * 128, col0 = blockIdx.y * 128;
  const bf16* pAh = Ah + (size_t)bz * sA + (size_t)row0 * lda;
  const bf16* pAl = Al + (size_t)bz * sA + (size_t)row0 * lda;
  const bf16* pBh = Bh + (size_t)bz * sB + (size_t)col0 * ldb;
  const bf16* pBl = Bl + (size_t)bz * sB + (size_t)col0 * ldb;

  auto stage = [&](int buf, int kt) {
    const int k0 = kt * 32;
#pragma unroll
    for (int i = 0; i < 2; i++) {
      const int sb = i * 256 + wave * 64;
      const int s = sb + lane;
      const int r = s >> 2, kseg = (s & 3) * 8;
      gld_lds16(pAh + (size_t)r * lda + k0 + kseg, &smA[buf][0][sb * 8]);
    }
#pragma unroll
    for (int i = 0; i < 2; i++) {
      const int sb = i * 256 + wave * 64;
      const int s = sb + lane;
      const int r = s >> 2, kseg = (s & 3) * 8;
      gld_lds16(pAl + (size_t)r * lda + k0 + kseg, &smA[buf][1][sb * 8]);
    }
#pragma unroll
    for (int i = 0; i < 2; i++) {
      const int sb = i * 256 + wave * 64;
      const int s = sb + lane;
      const int c = s >> 2, kseg = (s & 3) * 8;
      gld_lds16(pBh + (size_t)c * ldb + k0 + kseg, &smB[buf][0][sb * 8]);
    }
#pragma unroll
    for (int i = 0; i < 2; i++) {
      const int sb = i * 256 + wave * 64;
      const int s = sb + lane;
      const int c = s >> 2, kseg = (s & 3) * 8;
      gld_lds16(pBl + (size_t)c * ldb + k0 + kseg, &smB[buf][1][sb * 8]);
    }
  };

  f32x4 acc[4][4];
  const f32x4 zero = {0.f, 0.f, 0.f, 0.f};
#pragma unroll
  for (int i = 0; i < 4; i++)
#pragma unroll
    for (int j = 0; j < 4; j++) acc[i][j] = zero;

  const int wrow = (wave >> 1) * 64, wcol = (wave & 1) * 64;
  stage(0, 0);
  __syncthreads();
  int buf = 0;
  for (int kt = 0; kt < 16; kt++) {
    if (kt < 15) stage(buf ^ 1, kt + 1);
    bf16x8 afh[4], afl[4], bfh[4], bfl[4];
    const int kk = l4 * 8;
#pragma unroll
    for (int f = 0; f < 4; f++) {
      const int ar = wrow + f * 16 + l15;
      afh[f] = *(const bf16x8*)&smA[buf][0][ar * 32 + kk];
      afl[f] = *(const bf16x8*)&smA[buf][1][ar * 32 + kk];
      const int bc = wcol + f * 16 + l15;
      bfh[f] = *(const bf16x8*)&smB[buf][0][bc * 32 + kk];
      bfl[f] = *(const bf16x8*)&smB[buf][1][bc * 32 + kk];
    }
#pragma unroll
    for (int fi = 0; fi < 4; fi++)
#pragma unroll
      for (int fj = 0; fj < 4; fj++) {
        f32x4 c = acc[fi][fj];
        c = mfma16(afh[fi], bfh[fj], c);
        c = mfma16(afh[fi], bfl[fj], c);
        c = mfma16(afl[fi], bfh[fj], c);
        acc[fi][fj] = c;
      }
    __syncthreads();
    buf ^= 1;
  }
  bf16* pDh = Dh + (size_t)bz * sD;
  bf16* pDl = Dl + (size_t)bz * sD;
#pragma unroll
  for (int fi = 0; fi < 4; fi++)
#pragma unroll
    for (int fj = 0; fj < 4; fj++)
#pragma unroll
      for (int r = 0; r < 4; r++) {
        const int row = row0 + wrow + fi * 16 + l4 * 4 + r;
        const int col = col0 + wcol + fj * 16 + l15;
        const float v = acc[fi][fj][r];
        const bf16 h = (bf16)v;
        pDh[(size_t)row * ldd + col] = h;
        if (store_lo) pDl[(size_t)row * ldd + col] = (bf16)(v - (float)h);
      }
}

// ---------------- kernel 5: flash attention ---------------------------------
// grid 256 = (nb=16) x (ms=2) x (b=8), batch-per-XCD. 512 threads (8 waves).
// Per iter (32 m): wave computes QK^T for its own 16 n (48 MFMA, private
// online softmax), publishes P (sP) AND per-column corr (sCorr); barrier;
// PV re-partitioned by o: wave = 64 o x all 128 n, scales each acc column by
// its owner's corr, accumulates (32 MFMA). Unnorm. bf16 partials + stats.
__global__ __launch_bounds__(512, 2) void flash_kernel(
    const bf16* __restrict__ qkt_h, const bf16* __restrict__ qkt_l,
    const bf16* __restrict__ vmat, bf16* __restrict__ pacc,
    float* __restrict__ mstat, float* __restrict__ lstat) {
  __shared__ bf16 sK[2][2][32 * 256];  // [buf][hi/lo][m][k swizzled] 64KB
  __shared__ bf16 sV[2][512 * 32];     // [buf][o][m swizzled]        64KB
  __shared__ bf16 sP[128 * 32];        // [n][m swizzled]              8KB
  __shared__ float sCorr[128];         // per-n rescale factor        .5KB
  const int tid = threadIdx.x, wave = tid >> 6, lane = tid & 63;
  const int l15 = lane & 15, l4 = lane >> 4;
  // 256 blocks, 8 XCDs -> 32/XCD = one batch per XCD (bijective)
  const int bid = blockIdx.x;
  const int wgid = (bid & 7) * 32 + (bid >> 3);
  const int b = wgid >> 5, ms = (wgid >> 4) & 1, nb = wgid & 15;
  const int mbase = ms * 1024;
  const int nblk = nb * 128;
  const int n0w = nblk + wave * 16;
  const bf16* qh_base = qkt_h + (size_t)b * N_ * 512;
  const bf16* ql_base = qkt_l + (size_t)b * N_ * 512;
  const bf16* v_base = vmat + (size_t)b * CO_ * N_;

  // Q frags: wave's 16 n x 256 k, hi/lo (64 VGPR)
  bf16x8 qh[8], ql[8];
  {
    const size_t r0 = (size_t)(n0w + l15) * 512 + l4 * 8;
#pragma unroll
    for (int ks = 0; ks < 8; ks++) {
      qh[ks] = *(const bf16x8*)(qh_base + r0 + ks * 32);
      ql[ks] = *(const bf16x8*)(ql_base + r0 + ks * 32);
    }
  }

  f32x4 acc[4][8];  // [of (64 o)][nf (128 n)] = 128 f32
  const f32x4 zero = {0.f, 0.f, 0.f, 0.f};
#pragma unroll
  for (int of = 0; of < 4; of++)
#pragma unroll
    for (int nf = 0; nf < 8; nf++) acc[of][nf] = zero;
  float run_m = -3e38f, run_l = 0.f;

  // staging source offsets (iteration-invariant). Swizzles on SOURCE side:
  // sK 16B-slot: phys p holds logical L = p ^ ((m&7)<<2)  (XOR in ks bits)
  // sV granule:  phys p holds logical g = p ^ ((o>>1)&3)
  int offK[2], offV[4];
#pragma unroll
  for (int i = 0; i < 2; i++) {
    const int c = i * 512 + tid;  // 1024 K-chunks per hi/lo
    const int m = c >> 5, slot = c & 31;
    const int L = slot ^ ((m & 7) << 2);
    offK[i] = m * 512 + 256 + L * 8;  // K = cols 256..511 of qkt
  }
#pragma unroll
  for (int i = 0; i < 4; i++) {
    const int c = i * 512 + tid;  // 2048 V-chunks
    const int o = c >> 2, G = c & 3;
    offV[i] = o * N_ + (G ^ ((o >> 1) & 3)) * 8;
  }

  auto stage = [&](int bufi, int mt) {
    const int m0 = mbase + mt * 32;
    const int mK = m0 * 512;
#pragma unroll
    for (int i = 0; i < 2; i++) {
      const int db = (i * 512 + wave * 64) * 8;  // wave-uniform dest
      gld_lds16(qh_base + mK + offK[i], &sK[bufi][0][db]);
      gld_lds16(ql_base + mK + offK[i], &sK[bufi][1][db]);
    }
#pragma unroll
    for (int i = 0; i < 4; i++) {
      const int db = (i * 512 + wave * 64) * 8;
      gld_lds16(v_base + m0 + offV[i], &sV[bufi][db]);
    }
  };

  stage(0, 0);
  __syncthreads();
  int buf = 0;
  const int kb0 = l15 * 256, kb1 = (16 + l15) * 256;
  const int fP = (l15 >> 1) & 3;  // granule XOR for sP and sV reads

  for (int mt = 0; mt < 32; mt++) {
    if (mt < 31) stage(buf ^ 1, mt + 1);
    // ---- QK^T: wave's 16 n x 32 m, hi/lo 3-term (48 MFMA) ----
    f32x4 s0 = zero, s1 = zero;
#pragma unroll
    for (int ks = 0; ks < 8; ks++) {
      const int ke = ((ks ^ (l15 & 7)) * 32) + l4 * 8;  // ks-field XOR
      const bf16x8 kh0 = *(const bf16x8*)&sK[buf][0][kb0 + ke];
      const bf16x8 kl0 = *(const bf16x8*)&sK[buf][1][kb0 + ke];
      const bf16x8 kh1 = *(const bf16x8*)&sK[buf][0][kb1 + ke];
      const bf16x8 kl1 = *(const bf16x8*)&sK[buf][1][kb1 + ke];
      s0 = mfma16(kh0, qh[ks], s0);
      s1 = mfma16(kh1, qh[ks], s1);
      s0 = mfma16(kh0, ql[ks], s0);
      s1 = mfma16(kh1, ql[ks], s1);
      s0 = mfma16(kl0, qh[ks], s0);
      s1 = mfma16(kl1, qh[ks], s1);
    }
    // ---- online softmax (lane col n = n0w + l15; m spread over l4) ----
    float tmax = fmaxf(fmaxf(fmaxf(s0[0], s0[1]), fmaxf(s0[2], s0[3])),
                       fmaxf(fmaxf(s1[0], s1[1]), fmaxf(s1[2], s1[3])));
    tmax = fmaxf(tmax, __shfl_xor(tmax, 16));
    tmax = fmaxf(tmax, __shfl_xor(tmax, 32));
    const float nm = fmaxf(run_m, tmax);
    const float corr = __expf(run_m - nm);
    float ts = 0.f;
    bf16x4 p0, p1;
#pragma unroll
    for (int r = 0; r < 4; r++) {
      const float e0 = __expf(s0[r] - nm);
      const float e1 = __expf(s1[r] - nm);
      ts += e0 + e1;
      p0[r] = (bf16)e0;
      p1[r] = (bf16)e1;
    }
    {  // write P slice: rows n (wave*16+l15); granule-XOR by fP
      const int row = (wave * 16 + l15) * 32;
      const int g0 = (((l4 >> 1)) ^ fP) * 8 + (l4 & 1) * 4;      // m 0..15
      const int g1 = (((l4 >> 1) + 2) ^ fP) * 8 + (l4 & 1) * 4;  // m 16..31
      *(bf16x4*)&sP[row + g0] = p0;
      *(bf16x4*)&sP[row + g1] = p1;
    }
    ts += __shfl_xor(ts, 16);
    ts += __shfl_xor(ts, 32);
    run_l = run_l * corr + ts;
    run_m = nm;
    if (l4 == 0) sCorr[wave * 16 + l15] = corr;  // publish per-column corr
    __syncthreads();  // sP + sCorr visible to all waves
    // ---- PV: wave owns 64 o x all 128 n; rescale each col by its corr ----
    float cs[8];
#pragma unroll
    for (int nf = 0; nf < 8; nf++) cs[nf] = sCorr[nf * 16 + l15];
#pragma unroll
    for (int of = 0; of < 4; of++)
#pragma unroll
      for (int nf = 0; nf < 8; nf++) acc[of][nf] *= cs[nf];
    bf16x8 vf[4];
#pragma unroll
    for (int of = 0; of < 4; of++) {
      const int o = wave * 64 + of * 16 + l15;  // (o>>1)&3 == fP here
      vf[of] = *(const bf16x8*)&sV[buf][o * 32 + (l4 ^ fP) * 8];
    }
#pragma unroll
    for (int nf = 0; nf < 8; nf++) {
      const bf16x8 pb =
          *(const bf16x8*)&sP[(nf * 16 + l15) * 32 + (l4 ^ fP) * 8];
#pragma unroll
      for (int of = 0; of < 4; of++)
        acc[of][nf] = mfma16(vf[of], pb, acc[of][nf]);
    }
    __syncthreads();  // sP/sCorr/buffers safe to rewrite
    buf ^= 1;
  }
  // ---- epilogue: unnormalized bf16 partial + stats ----
  bf16* pbase = pacc + (size_t)ms * ((size_t)B_ * CO_ * N_) +
                (size_t)b * CO_ * N_;
#pragma unroll
  for (int of = 0; of < 4; of++)
#pragma unroll
    for (int nf = 0; nf < 8; nf++)
#pragma unroll
      for (int r = 0; r < 4; r++) {
        const int o = wave * 64 + of * 16 + l4 * 4 + r;
        const int n = nblk + nf * 16 + l15;
        pbase[(size_t)o * N_ + n] = (bf16)acc[of][nf][r];
      }
  if (l4 == 0) {
    const int si = ms * (B_ * N_) + b * N_ + n0w + l15;
    mstat[si] = run_m;
    lstat[si] = run_l;
  }
}

// ---------------- kernel 6: combine the two m-split partials ----------------
__global__ __launch_bounds__(256) void combine_kernel(
    const bf16* __restrict__ pacc, const float* __restrict__ mstat,
    const float* __restrict__ lstat, float* __restrict__ out) {
  const size_t XT = (size_t)B_ * CO_ * N_;
  const size_t t = (size_t)blockIdx.x * 256 + threadIdx.x;  // 1,048,576
  const int n0 = (int)(t & 255) * 8;
  const int o = (int)((t >> 8) & 511);
  const int b = (int)(t >> 17);
  const size_t po = ((size_t)b * CO_ + o) * N_ + n0;
  const bf16x8 p1 = *(const bf16x8*)(pacc + po);
  const bf16x8 p2 = *(const bf16x8*)(pacc + XT + po);
  const int sb = b * N_ + n0;
  f32x4 r0, r1;
#pragma unroll
  for (int j = 0; j < 8; j++) {
    const float m1 = mstat[sb + j], m2 = mstat[B_ * N_ + sb + j];
    const float l1 = lstat[sb + j], l2 = lstat[B_ * N_ + sb + j];
    const float M = fmaxf(m1, m2);
    const float a1 = __expf(m1 - M), a2 = __expf(m2 - M);
    const float L = a1 * l1 + a2 * l2;
    const float v = ((float)p1[j] * a1 + (float)p2[j] * a2) / L;
    if (j < 4) r0[j] = v; else r1[j - 4] = v;
  }
  *(f32x4*)(out + po) = r0;
  *(f32x4*)(out + po + 4) = r1;
}

// ---------------- launcher ---------------------------------------------------
extern "C" void kernel_launch(void* const* d_in, const int* in_sizes, int n_in,
                              void* d_out, int out_size, void* d_ws,
                              size_t ws_size, hipStream_t stream) {
  const float* x = (const float*)d_in[0];
  const float* Wq = (const float*)d_in[1];
  const float* Wk = (const float*)d_in[2];
  const float* Wv = (const float*)d_in[3];
  float* out = (float*)d_out;
  bf16* ws = (bf16*)d_ws;

  const size_t XT = (size_t)B_ * N_ * CIN_;  // 8,388,608 elems (== B*Co*N)
  const size_t XTB = (size_t)N_ * CIN_;      // per-batch stride
  bf16* qk_h = ws;
  bf16* qk_l = ws + XT;
  bf16* v_h = ws + 2 * XT;
  bf16* xt_h = ws + 3 * XT;  // dead after gemms -> aliased by partials
  bf16* xt_l = ws + 4 * XT;
  bf16* pacc = xt_h;         // 2*XT bf16 partials
  bf16* w_h = ws + 5 * XT;
  bf16* w_l = w_h + 1024 * 512;
  float* mstat = (float*)(w_l + 1024 * 512);  // [2][8][2048] f32
  float* lstat = mstat + 2 * B_ * N_;
  // total ws use ~86.5 MB

  xt_kernel<<<dim3(64, 16, 8), dim3(32, 8, 1), 0, stream>>>(x, xt_h, xt_l);
  w_kernel<<<dim3(2048), dim3(256), 0, stream>>>(Wq, Wk, Wv, w_h, w_l);
  // QKt (B, N, 512): rows n, cols (Q|K)
  gemm_hilo<<<dim3(16, 4, 8), dim3(256), 0, stream>>>(
      xt_h, xt_l, XTB, w_h, w_l, (size_t)0, qk_h, qk_l, XTB, 512, 512, 512, 1);
  // V (B, 512, N): rows o, cols n (no lo stored)
  gemm_hilo<<<dim3(4, 16, 8), dim3(256), 0, stream>>>(
      w_h + 512 * 512, w_l + 512 * 512, (size_t)0, xt_h, xt_l, XTB, v_h, v_h,
      (size_t)(CO_ * N_), 512, 512, 2048, 0);
  flash_kernel<<<dim3(256), dim3(512), 0, stream>>>(qk_h, qk_l, v_h, pacc,
                                                    mstat, lstat);
  combine_kernel<<<dim3(4096), dim3(256), 0, stream>>>(pacc, mstat, lstat, out);
}

// Round 10
// 265.465 us; speedup vs baseline: 1.9210x; 1.0580x over previous
//
#include <hip/hip_runtime.h>
#include <hip/hip_bf16.h>

// Shapes (fixed): B=8, Cin=512, N=2048, Ck=256, Co=512.
// hi/lo bf16 split for projections + QK^T; plain bf16 for V-GEMM and P*V.
// R9 changes vs R8 (280.9us total, flash 120us, conflicts 8.9e6):
//  - sK swizzle granularity FIX: R8 XOR'd in 4-slot units ((m&7)<<2) -> banks
//    collapse to 2 quads = 8-way conflict (the 8.9e6). Now 1-slot granular:
//    write L = slot^(m&7); read phys_slot = (ks*4+l4)^(l15&7) -> 2-way (free).
//  - V GEMM single-term plain bf16 (V~N(0,1); 1-term error ~1e-3 << thr):
//    gemm_hilo gains nterms, V call stages hi only, 16 MFMA/iter vs 48.
// Occupancy note: flash is register-capped (acc 128 + Q 64) at 8 waves/CU;
// LDS shrink can't add blocks, so attack stalls (conflicts), not TLP.
// (R10 = identical resubmit; R9 bench was a broker timeout, no data.)

typedef __bf16 bf16;
typedef __bf16 bf16x8 __attribute__((ext_vector_type(8)));
typedef __bf16 bf16x4 __attribute__((ext_vector_type(4)));
typedef float  f32x4  __attribute__((ext_vector_type(4)));

#define B_   8
#define N_   2048
#define CIN_ 512
#define CO_  512

__device__ __forceinline__ f32x4 mfma16(bf16x8 a, bf16x8 b, f32x4 c) {
  return __builtin_amdgcn_mfma_f32_16x16x32_bf16(a, b, c, 0, 0, 0);
}

__device__ __forceinline__ void gld_lds16(const bf16* g, bf16* l) {
  __builtin_amdgcn_global_load_lds(
      (const __attribute__((address_space(1))) void*)g,
      (__attribute__((address_space(3))) void*)l,
      16, 0, 0);
}

// ---------------- kernel 1: x (B,Cin,N) f32 -> xt (B,N,Cin) hi/lo bf16 ------
__global__ __launch_bounds__(256) void xt_kernel(const float* __restrict__ x,
                                                 bf16* __restrict__ xt_h,
                                                 bf16* __restrict__ xt_l) {
  __shared__ float tile[32][33];
  const int b = blockIdx.z;
  const int n0 = blockIdx.x * 32, c0 = blockIdx.y * 32;
  const int tx = threadIdx.x, ty = threadIdx.y;  // (32, 8)
  const float* xp = x + (size_t)b * CIN_ * N_;
#pragma unroll
  for (int j = 0; j < 4; j++)
    tile[ty + 8 * j][tx] = xp[(size_t)(c0 + ty + 8 * j) * N_ + n0 + tx];
  __syncthreads();
#pragma unroll
  for (int j = 0; j < 4; j++) {
    const int nl = ty + 8 * j, cl = tx;
    const float v = tile[cl][nl];
    const bf16 h = (bf16)v;
    const size_t o = (size_t)b * N_ * CIN_ + (size_t)(n0 + nl) * CIN_ + c0 + cl;
    xt_h[o] = h;
    xt_l[o] = (bf16)(v - (float)h);
  }
}

// ---------------- kernel 2: W rows [Wq(256); Wk(256); Wv(512)] -> hi/lo -----
__global__ __launch_bounds__(256) void w_kernel(const float* __restrict__ Wq,
                                                const float* __restrict__ Wk,
                                                const float* __restrict__ Wv,
                                                bf16* __restrict__ w_h,
                                                bf16* __restrict__ w_l) {
  const int idx = blockIdx.x * 256 + threadIdx.x;  // < 1024*512
  const int row = idx >> 9;
  float v;
  if (row < 256)       v = Wq[idx];
  else if (row < 512)  v = Wk[idx - 256 * 512];
  else                 v = Wv[idx - 512 * 512];
  const bf16 h = (bf16)v;
  w_h[idx] = h;
  w_l[idx] = (bf16)(v - (float)h);
}

// ---------------- kernel 3/4: GEMM, D[row,col] = sum_k A[row,k]B[col,k] -----
// nterms==3: hi/lo 3-MFMA fp32 emulation. nterms==1: plain bf16 (hi only).
__global__ __launch_bounds__(256) void gemm_hilo(
    const bf16* __restrict__ Ah, const bf16* __restrict__ Al, size_t sA,
    const bf16* __restrict__ Bh, const bf16* __restrict__ Bl, size_t sB,
    bf16* __restrict__ Dh, bf16* __restrict__ Dl, size_t sD,
    int lda, int ldb, int ldd, int store_lo, int nterms) {
  __shared__ bf16 smA[2][2][128 * 32];  // [buf][hi/lo][row][k]
  __shared__ bf16 smB[2][2][128 * 32];  // [buf][hi/lo][col][k]
  const int tid = threadIdx.x;
  const int wave = tid >> 6, lane = tid & 63;
  const int l15 = lane & 15, l4 = lane >> 4;
  const int bz = blockIdx.z;
  const int row0 = blockIdx.x * 128, col0 = blockIdx.y * 128;
  const bf16* pAh = Ah + (size_t)bz * sA + (size_t)row0 * lda;
  const bf16* pAl = Al + (size_t)bz * sA + (size_t)row0 * lda;
  const bf16* pBh = Bh + (size_t)bz * sB + (size_t)col0 * ldb;
  const bf16* pBl = Bl + (size_t)bz * sB + (size_t)col0 * ldb;

  auto stage = [&](int buf, int kt) {
    const int k0 = kt * 32;
#pragma unroll
    for (int i = 0; i < 2; i++) {
      const int sb = i * 256 + wave * 64;
      const int s = sb + lane;
      const int r = s >> 2, kseg = (s & 3) * 8;
      gld_lds16(pAh + (size_t)r * lda + k0 + kseg, &smA[buf][0][sb * 8]);
    }
#pragma unroll
    for (int i = 0; i < 2; i++) {
      const int sb = i * 256 + wave * 64;
      const int s = sb + lane;
      const int c = s >> 2, kseg = (s & 3) * 8;
      gld_lds16(pBh + (size_t)c * ldb + k0 + kseg, &smB[buf][0][sb * 8]);
    }
    if (nterms == 3) {
#pragma unroll
      for (int i = 0; i < 2; i++) {
        const int sb = i * 256 + wave * 64;
        const int s = sb + lane;
        const int r = s >> 2, kseg = (s & 3) * 8;
        gld_lds16(pAl + (size_t)r * lda + k0 + kseg, &smA[buf][1][sb * 8]);
      }
#pragma unroll
      for (int i = 0; i < 2; i++) {
        const int sb = i * 256 + wave * 64;
        const int s = sb + lane;
        const int c = s >> 2, kseg = (s & 3) * 8;
        gld_lds16(pBl + (size_t)c * ldb + k0 + kseg, &smB[buf][1][sb * 8]);
      }
    }
  };

  f32x4 acc[4][4];
  const f32x4 zero = {0.f, 0.f, 0.f, 0.f};
#pragma unroll
  for (int i = 0; i < 4; i++)
#pragma unroll
    for (int j = 0; j < 4; j++) acc[i][j] = zero;

  const int wrow = (wave >> 1) * 64, wcol = (wave & 1) * 64;
  stage(0, 0);
  __syncthreads();
  int buf = 0;
  for (int kt = 0; kt < 16; kt++) {
    if (kt < 15) stage(buf ^ 1, kt + 1);
    bf16x8 afh[4], afl[4], bfh[4], bfl[4];
    const int kk = l4 * 8;
#pragma unroll
    for (int f = 0; f < 4; f++) {
      const int ar = wrow + f * 16 + l15;
      afh[f] = *(const bf16x8*)&smA[buf][0][ar * 32 + kk];
      const int bc = wcol + f * 16 + l15;
      bfh[f] = *(const bf16x8*)&smB[buf][0][bc * 32 + kk];
      if (nterms == 3) {
        afl[f] = *(const bf16x8*)&smA[buf][1][ar * 32 + kk];
        bfl[f] = *(const bf16x8*)&smB[buf][1][bc * 32 + kk];
      }
    }
#pragma unroll
    for (int fi = 0; fi < 4; fi++)
#pragma unroll
      for (int fj = 0; fj < 4; fj++) {
        f32x4 c = acc[fi][fj];
        c = mfma16(afh[fi], bfh[fj], c);
        if (nterms == 3) {
          c = mfma16(afh[fi], bfl[fj], c);
          c = mfma16(afl[fi], bfh[fj], c);
        }
        acc[fi][fj] = c;
      }
    __syncthreads();
    buf ^= 1;
  }
  bf16* pDh = Dh + (size_t)bz * sD;
  bf16* pDl = Dl + (size_t)bz * sD;
#pragma unroll
  for (int fi = 0; fi < 4; fi++)
#pragma unroll
    for (int fj = 0; fj < 4; fj++)
#pragma unroll
      for (int r = 0; r < 4; r++) {
        const int row = row0 + wrow + fi * 16 + l4 * 4 + r;
        const int col = col0 + wcol + fj * 16 + l15;
        const float v = acc[fi][fj][r];
        const bf16 h = (bf16)v;
        pDh[(size_t)row * ldd + col] = h;
        if (store_lo) pDl[(size_t)row * ldd + col] = (bf16)(v - (float)h);
      }
}

// ---------------- kernel 5: flash attention ---------------------------------
// grid 256 = (nb=16) x (ms=2) x (b=8), batch-per-XCD. 512 threads (8 waves).
// Per iter (32 m): wave computes QK^T for its own 16 n (48 MFMA, private
// online softmax), publishes P (sP) AND per-column corr (sCorr); barrier;
// PV re-partitioned by o: wave = 64 o x all 128 n, scales each acc column by
// its owner's corr, accumulates (32 MFMA). Unnorm. bf16 partials + stats.
// sK swizzle: 1-slot-granular XOR (slot^(m&7)) -> 2-way (free) b128 reads.
__global__ __launch_bounds__(512, 2) void flash_kernel(
    const bf16* __restrict__ qkt_h, const bf16* __restrict__ qkt_l,
    const bf16* __restrict__ vmat, bf16* __restrict__ pacc,
    float* __restrict__ mstat, float* __restrict__ lstat) {
  __shared__ bf16 sK[2][2][32 * 256];  // [buf][hi/lo][m][k swizzled] 64KB
  __shared__ bf16 sV[2][512 * 32];     // [buf][o][m swizzled]        64KB
  __shared__ bf16 sP[128 * 32];        // [n][m swizzled]              8KB
  __shared__ float sCorr[128];         // per-n rescale factor        .5KB
  const int tid = threadIdx.x, wave = tid >> 6, lane = tid & 63;
  const int l15 = lane & 15, l4 = lane >> 4;
  // 256 blocks, 8 XCDs -> 32/XCD = one batch per XCD (bijective)
  const int bid = blockIdx.x;
  const int wgid = (bid & 7) * 32 + (bid >> 3);
  const int b = wgid >> 5, ms = (wgid >> 4) & 1, nb = wgid & 15;
  const int mbase = ms * 1024;
  const int nblk = nb * 128;
  const int n0w = nblk + wave * 16;
  const bf16* qh_base = qkt_h + (size_t)b * N_ * 512;
  const bf16* ql_base = qkt_l + (size_t)b * N_ * 512;
  const bf16* v_base = vmat + (size_t)b * CO_ * N_;

  // Q frags: wave's 16 n x 256 k, hi/lo (64 VGPR)
  bf16x8 qh[8], ql[8];
  {
    const size_t r0 = (size_t)(n0w + l15) * 512 + l4 * 8;
#pragma unroll
    for (int ks = 0; ks < 8; ks++) {
      qh[ks] = *(const bf16x8*)(qh_base + r0 + ks * 32);
      ql[ks] = *(const bf16x8*)(ql_base + r0 + ks * 32);
    }
  }

  f32x4 acc[4][8];  // [of (64 o)][nf (128 n)] = 128 f32
  const f32x4 zero = {0.f, 0.f, 0.f, 0.f};
#pragma unroll
  for (int of = 0; of < 4; of++)
#pragma unroll
    for (int nf = 0; nf < 8; nf++) acc[of][nf] = zero;
  float run_m = -3e38f, run_l = 0.f;

  // staging source offsets (iteration-invariant). Swizzles on SOURCE side:
  // sK: phys 16B-slot p of row m holds logical slot p^(m&7)  (1-slot XOR)
  // sV: phys granule p of row o holds logical g = p ^ ((o>>1)&3)
  int offK[2], offV[4];
#pragma unroll
  for (int i = 0; i < 2; i++) {
    const int c = i * 512 + tid;  // 1024 K-chunks per hi/lo
    const int m = c >> 5, slot = c & 31;
    const int L = slot ^ (m & 7);
    offK[i] = m * 512 + 256 + L * 8;  // K = cols 256..511 of qkt
  }
#pragma unroll
  for (int i = 0; i < 4; i++) {
    const int c = i * 512 + tid;  // 2048 V-chunks
    const int o = c >> 2, G = c & 3;
    offV[i] = o * N_ + (G ^ ((o >> 1) & 3)) * 8;
  }

  auto stage = [&](int bufi, int mt) {
    const int m0 = mbase + mt * 32;
    const int mK = m0 * 512;
#pragma unroll
    for (int i = 0; i < 2; i++) {
      const int db = (i * 512 + wave * 64) * 8;  // wave-uniform dest
      gld_lds16(qh_base + mK + offK[i], &sK[bufi][0][db]);
      gld_lds16(ql_base + mK + offK[i], &sK[bufi][1][db]);
    }
#pragma unroll
    for (int i = 0; i < 4; i++) {
      const int db = (i * 512 + wave * 64) * 8;
      gld_lds16(v_base + m0 + offV[i], &sV[bufi][db]);
    }
  };

  stage(0, 0);
  __syncthreads();
  int buf = 0;
  const int kb0 = l15 * 256, kb1 = (16 + l15) * 256;
  const int fP = (l15 >> 1) & 3;  // granule XOR for sP and sV reads

  for (int mt = 0; mt < 32; mt++) {
    if (mt < 31) stage(buf ^ 1, mt + 1);
    // ---- QK^T: wave's 16 n x 32 m, hi/lo 3-term (48 MFMA) ----
    f32x4 s0 = zero, s1 = zero;
#pragma unroll
    for (int ks = 0; ks < 8; ks++) {
      // logical slot ks*4+l4, row m=l15 (and 16+l15: same &7) -> phys slot
      const int ke = ((ks * 4 + l4) ^ (l15 & 7)) * 8;
      const bf16x8 kh0 = *(const bf16x8*)&sK[buf][0][kb0 + ke];
      const bf16x8 kl0 = *(const bf16x8*)&sK[buf][1][kb0 + ke];
      const bf16x8 kh1 = *(const bf16x8*)&sK[buf][0][kb1 + ke];
      const bf16x8 kl1 = *(const bf16x8*)&sK[buf][1][kb1 + ke];
      s0 = mfma16(kh0, qh[ks], s0);
      s1 = mfma16(kh1, qh[ks], s1);
      s0 = mfma16(kh0, ql[ks], s0);
      s1 = mfma16(kh1, ql[ks], s1);
      s0 = mfma16(kl0, qh[ks], s0);
      s1 = mfma16(kl1, qh[ks], s1);
    }
    // ---- online softmax (lane col n = n0w + l15; m spread over l4) ----
    float tmax = fmaxf(fmaxf(fmaxf(s0[0], s0[1]), fmaxf(s0[2], s0[3])),
                       fmaxf(fmaxf(s1[0], s1[1]), fmaxf(s1[2], s1[3])));
    tmax = fmaxf(tmax, __shfl_xor(tmax, 16));
    tmax = fmaxf(tmax, __shfl_xor(tmax, 32));
    const float nm = fmaxf(run_m, tmax);
    const float corr = __expf(run_m - nm);
    float ts = 0.f;
    bf16x4 p0, p1;
#pragma unroll
    for (int r = 0; r < 4; r++) {
      const float e0 = __expf(s0[r] - nm);
      const float e1 = __expf(s1[r] - nm);
      ts += e0 + e1;
      p0[r] = (bf16)e0;
      p1[r] = (bf16)e1;
    }
    {  // write P slice: rows n (wave*16+l15); granule-XOR by fP
      const int row = (wave * 16 + l15) * 32;
      const int g0 = (((l4 >> 1)) ^ fP) * 8 + (l4 & 1) * 4;      // m 0..15
      const int g1 = (((l4 >> 1) + 2) ^ fP) * 8 + (l4 & 1) * 4;  // m 16..31
      *(bf16x4*)&sP[row + g0] = p0;
      *(bf16x4*)&sP[row + g1] = p1;
    }
    ts += __shfl_xor(ts, 16);
    ts += __shfl_xor(ts, 32);
    run_l = run_l * corr + ts;
    run_m = nm;
    if (l4 == 0) sCorr[wave * 16 + l15] = corr;  // publish per-column corr
    __syncthreads();  // sP + sCorr visible to all waves
    // ---- PV: wave owns 64 o x all 128 n; rescale each col by its corr ----
    float cs[8];
#pragma unroll
    for (int nf = 0; nf < 8; nf++) cs[nf] = sCorr[nf * 16 + l15];
#pragma unroll
    for (int of = 0; of < 4; of++)
#pragma unroll
      for (int nf = 0; nf < 8; nf++) acc[of][nf] *= cs[nf];
    bf16x8 vf[4];
#pragma unroll
    for (int of = 0; of < 4; of++) {
      const int o = wave * 64 + of * 16 + l15;  // (o>>1)&3 == fP here
      vf[of] = *(const bf16x8*)&sV[buf][o * 32 + (l4 ^ fP) * 8];
    }
#pragma unroll
    for (int nf = 0; nf < 8; nf++) {
      const bf16x8 pb =
          *(const bf16x8*)&sP[(nf * 16 + l15) * 32 + (l4 ^ fP) * 8];
#pragma unroll
      for (int of = 0; of < 4; of++)
        acc[of][nf] = mfma16(vf[of], pb, acc[of][nf]);
    }
    __syncthreads();  // sP/sCorr/buffers safe to rewrite
    buf ^= 1;
  }
  // ---- epilogue: unnormalized bf16 partial + stats ----
  bf16* pbase = pacc + (size_t)ms * ((size_t)B_ * CO_ * N_) +
                (size_t)b * CO_ * N_;
#pragma unroll
  for (int of = 0; of < 4; of++)
#pragma unroll
    for (int nf = 0; nf < 8; nf++)
#pragma unroll
      for (int r = 0; r < 4; r++) {
        const int o = wave * 64 + of * 16 + l4 * 4 + r;
        const int n = nblk + nf * 16 + l15;
        pbase[(size_t)o * N_ + n] = (bf16)acc[of][nf][r];
      }
  if (l4 == 0) {
    const int si = ms * (B_ * N_) + b * N_ + n0w + l15;
    mstat[si] = run_m;
    lstat[si] = run_l;
  }
}

// ---------------- kernel 6: combine the two m-split partials ----------------
__global__ __launch_bounds__(256) void combine_kernel(
    const bf16* __restrict__ pacc, const float* __restrict__ mstat,
    const float* __restrict__ lstat, float* __restrict__ out) {
  const size_t XT = (size_t)B_ * CO_ * N_;
  const size_t t = (size_t)blockIdx.x * 256 + threadIdx.x;  // 1,048,576
  const int n0 = (int)(t & 255) * 8;
  const int o = (int)((t >> 8) & 511);
  const int b = (int)(t >> 17);
  const size_t po = ((size_t)b * CO_ + o) * N_ + n0;
  const bf16x8 p1 = *(const bf16x8*)(pacc + po);
  const bf16x8 p2 = *(const bf16x8*)(pacc + XT + po);
  const int sb = b * N_ + n0;
  f32x4 r0, r1;
#pragma unroll
  for (int j = 0; j < 8; j++) {
    const float m1 = mstat[sb + j], m2 = mstat[B_ * N_ + sb + j];
    const float l1 = lstat[sb + j], l2 = lstat[B_ * N_ + sb + j];
    const float M = fmaxf(m1, m2);
    const float a1 = __expf(m1 - M), a2 = __expf(m2 - M);
    const float L = a1 * l1 + a2 * l2;
    const float v = ((float)p1[j] * a1 + (float)p2[j] * a2) / L;
    if (j < 4) r0[j] = v; else r1[j - 4] = v;
  }
  *(f32x4*)(out + po) = r0;
  *(f32x4*)(out + po + 4) = r1;
}

// ---------------- launcher ---------------------------------------------------
extern "C" void kernel_launch(void* const* d_in, const int* in_sizes, int n_in,
                              void* d_out, int out_size, void* d_ws,
                              size_t ws_size, hipStream_t stream) {
  const float* x = (const float*)d_in[0];
  const float* Wq = (const float*)d_in[1];
  const float* Wk = (const float*)d_in[2];
  const float* Wv = (const float*)d_in[3];
  float* out = (float*)d_out;
  bf16* ws = (bf16*)d_ws;

  const size_t XT = (size_t)B_ * N_ * CIN_;  // 8,388,608 elems (== B*Co*N)
  const size_t XTB = (size_t)N_ * CIN_;      // per-batch stride
  bf16* qk_h = ws;
  bf16* qk_l = ws + XT;
  bf16* v_h = ws + 2 * XT;
  bf16* xt_h = ws + 3 * XT;  // dead after gemms -> aliased by partials
  bf16* xt_l = ws + 4 * XT;
  bf16* pacc = xt_h;         // 2*XT bf16 partials
  bf16* w_h = ws + 5 * XT;
  bf16* w_l = w_h + 1024 * 512;
  float* mstat = (float*)(w_l + 1024 * 512);  // [2][8][2048] f32
  float* lstat = mstat + 2 * B_ * N_;
  // total ws use ~86.5 MB

  xt_kernel<<<dim3(64, 16, 8), dim3(32, 8, 1), 0, stream>>>(x, xt_h, xt_l);
  w_kernel<<<dim3(2048), dim3(256), 0, stream>>>(Wq, Wk, Wv, w_h, w_l);
  // QKt (B, N, 512): rows n, cols (Q|K) — hi/lo 3-term, store lo
  gemm_hilo<<<dim3(16, 4, 8), dim3(256), 0, stream>>>(
      xt_h, xt_l, XTB, w_h, w_l, (size_t)0, qk_h, qk_l, XTB, 512, 512, 512, 1,
      3);
  // V (B, 512, N): rows o, cols n — plain bf16 single-term, hi only
  gemm_hilo<<<dim3(4, 16, 8), dim3(256), 0, stream>>>(
      w_h + 512 * 512, w_l + 512 * 512, (size_t)0, xt_h, xt_l, XTB, v_h, v_h,
      (size_t)(CO_ * N_), 512, 512, 2048, 0, 1);
  flash_kernel<<<dim3(256), dim3(512), 0, stream>>>(qk_h, qk_l, v_h, pacc,
                                                    mstat, lstat);
  combine_kernel<<<dim3(4096), dim3(256), 0, stream>>>(pacc, mstat, lstat, out);
}